// Round 2
// baseline (3554.734 us; speedup 1.0000x reference)
//
#include <hip/hip_runtime.h>

typedef _Float16 half8 __attribute__((ext_vector_type(8)));
typedef _Float16 half4 __attribute__((ext_vector_type(4)));
typedef float f32x4 __attribute__((ext_vector_type(4)));

// ---- ws layout (offsets in halves). All matrices have K=128 -> 4 k-chunks.
// frag layout: idx = (((nt*4 + kc)*64) + lane)*8 + j  ==  element index e itself.
constexpr int OFF_W0HI   = 0;        // 16384
constexpr int OFF_W0LO   = 16384;
constexpr int OFF_WL     = 32768;    // + m*32768 (hi), +16384 (lo), m=0..2
constexpr int OFF_WFHI   = 131072;   // 262144
constexpr int OFF_WFLO   = 393216;
constexpr int OFF_WLASTHI = 655360;  // 8192
constexpr int OFF_WLASTLO = 663552;  // total 671744 halves = 1.31 MB

// ---- dynamic LDS layout (bytes)
constexpr int L_ZS   = 0;        // float [32][132]  = 16896 B (padded stride!)
constexpr int L_KS   = 16896;    // float [3][32][128] = 49152 B
constexpr int L_DX   = 66048;    // float [32][16] = 2048 B
constexpr int L_ACT  = 68096;    // 6 x _Float16[32][136] (8704 B each)
constexpr int L_BIAS = 120320;   // float [2624]  (b0|bl|bf|b_last) = 10496 B
constexpr int LDS_BYTES = 130816;

__device__ __forceinline__ void cvt_elem(const float* __restrict__ W,
                                         _Float16* __restrict__ hi,
                                         _Float16* __restrict__ lo, int e) {
  int j  = e & 7;
  int l  = (e >> 3) & 63;
  int r  = e >> 9;
  int kc = r & 3;
  int nt = r >> 2;
  int row = nt * 16 + (l & 15);
  int col = kc * 32 + ((l >> 4) << 3) + j;
  float v = W[row * 128 + col];
  _Float16 h = (_Float16)v;
  hi[e] = h;
  lo[e] = (_Float16)(v - (float)h);
}

__global__ __launch_bounds__(256) void prep_kernel(const float* __restrict__ W0,
                                                   const float* __restrict__ Wl,
                                                   const float* __restrict__ Wf,
                                                   const float* __restrict__ Wlast,
                                                   _Float16* __restrict__ ws) {
  int e = blockIdx.x * 256 + threadIdx.x;
  if (e < 16384) {
    cvt_elem(W0, ws + OFF_W0HI, ws + OFF_W0LO, e);
  } else if (e < 65536) {
    int ee = e - 16384;
    int m = ee >> 14;
    ee &= 16383;
    cvt_elem(Wl + m * 16384, ws + OFF_WL + m * 32768,
             ws + OFF_WL + m * 32768 + 16384, ee);
  } else if (e < 327680) {
    cvt_elem(Wf, ws + OFF_WFHI, ws + OFF_WFLO, e - 65536);
  } else if (e < 335872) {
    cvt_elem(Wlast, ws + OFF_WLASTHI, ws + OFF_WLASTLO, e - 327680);
  }
}

template <int PAT>
__device__ __forceinline__ float swz_add(float v) {
  return v + __int_as_float(__builtin_amdgcn_ds_swizzle(__float_as_int(v), PAT));
}

// hidden layer, 2 stacked A-tiles share every B-fragment load
__device__ __forceinline__ void hidden_layer_pair(
    const _Float16* __restrict__ srcHi, const _Float16* __restrict__ srcLo,
    _Float16* __restrict__ dstHi, _Float16* __restrict__ dstLo,
    const _Float16* __restrict__ wHi, const _Float16* __restrict__ wLo,
    const float* __restrict__ bias, int w, int row, int g) {
  f32x4 acc0 = {0.f, 0.f, 0.f, 0.f}, acc1 = {0.f, 0.f, 0.f, 0.f};
  const int lane = g * 16 + row;
#pragma unroll
  for (int kc = 0; kc < 4; ++kc) {
    half8 bh  = *(const half8*)(wHi + w * 2048 + (kc * 64 + lane) * 8);
    half8 bl  = *(const half8*)(wLo + w * 2048 + (kc * 64 + lane) * 8);
    half8 ah0 = *(const half8*)(srcHi + row * 136 + kc * 32 + g * 8);
    half8 al0 = *(const half8*)(srcLo + row * 136 + kc * 32 + g * 8);
    half8 ah1 = *(const half8*)(srcHi + (row + 16) * 136 + kc * 32 + g * 8);
    half8 al1 = *(const half8*)(srcLo + (row + 16) * 136 + kc * 32 + g * 8);
    acc0 = __builtin_amdgcn_mfma_f32_16x16x32_f16(ah0, bh, acc0, 0, 0, 0);
    acc1 = __builtin_amdgcn_mfma_f32_16x16x32_f16(ah1, bh, acc1, 0, 0, 0);
    acc0 = __builtin_amdgcn_mfma_f32_16x16x32_f16(al0, bh, acc0, 0, 0, 0);
    acc1 = __builtin_amdgcn_mfma_f32_16x16x32_f16(al1, bh, acc1, 0, 0, 0);
    acc0 = __builtin_amdgcn_mfma_f32_16x16x32_f16(ah0, bl, acc0, 0, 0, 0);
    acc1 = __builtin_amdgcn_mfma_f32_16x16x32_f16(ah1, bl, acc1, 0, 0, 0);
  }
  int n = w * 16 + row;
  float bv = bias[n];
#pragma unroll
  for (int r = 0; r < 4; ++r) {
    float v0 = fmaxf(acc0[r] + bv, 0.f);
    _Float16 h0 = (_Float16)v0;
    dstHi[(g * 4 + r) * 136 + n] = h0;
    dstLo[(g * 4 + r) * 136 + n] = (_Float16)(v0 - (float)h0);
    float v1 = fmaxf(acc1[r] + bv, 0.f);
    _Float16 h1 = (_Float16)v1;
    dstHi[(16 + g * 4 + r) * 136 + n] = h1;
    dstLo[(16 + g * 4 + r) * 136 + n] = (_Float16)(v1 - (float)h1);
  }
}

__device__ __forceinline__ void out_gemm(int tt, int gb0, int w, int row, int g,
                                         const float* __restrict__ zS,
                                         const _Float16* __restrict__ ws,
                                         const float* __restrict__ biasS,
                                         float* __restrict__ out) {
  const int rbase = (w >> 2) * 16;   // which A-tile (rows)
  const int wn = w & 3;              // which 16-wide out tile
  f32x4 acc = {0.f, 0.f, 0.f, 0.f};
  const int lane = g * 16 + row;
#pragma unroll
  for (int kc = 0; kc < 4; ++kc) {
    const float* zp = zS + (rbase + row) * 132 + kc * 32 + g * 8;
    f32x4 z0 = *(const f32x4*)zp;
    f32x4 z1 = *(const f32x4*)(zp + 4);
    half8 ah, al;
#pragma unroll
    for (int j = 0; j < 4; ++j) {
      _Float16 h = (_Float16)z0[j];
      ah[j] = h; al[j] = (_Float16)(z0[j] - (float)h);
      _Float16 h2 = (_Float16)z1[j];
      ah[4 + j] = h2; al[4 + j] = (_Float16)(z1[j] - (float)h2);
    }
    half8 bh = *(const half8*)(ws + OFF_WLASTHI + wn * 2048 + (kc * 64 + lane) * 8);
    half8 bl = *(const half8*)(ws + OFF_WLASTLO + wn * 2048 + (kc * 64 + lane) * 8);
    acc = __builtin_amdgcn_mfma_f32_16x16x32_f16(ah, bh, acc, 0, 0, 0);
    acc = __builtin_amdgcn_mfma_f32_16x16x32_f16(al, bh, acc, 0, 0, 0);
    acc = __builtin_amdgcn_mfma_f32_16x16x32_f16(ah, bl, acc, 0, 0, 0);
  }
  int o = wn * 16 + row;
  float bv = biasS[2560 + o];
#pragma unroll
  for (int r = 0; r < 4; ++r) {
    float x = acc[r] + bv;
    float sg = __fdividef(1.f, 1.f + __expf(-x));
    out[((size_t)(gb0 + rbase + g * 4 + r) * 32 + tt) * 64 + o] = sg;
  }
}

__global__ __launch_bounds__(512) void cde_kernel(
    const float* __restrict__ coeffs, const float* __restrict__ W_init,
    const float* __restrict__ b_init, const float* __restrict__ b0,
    const float* __restrict__ bl, const float* __restrict__ bf,
    const float* __restrict__ b_last, const _Float16* __restrict__ ws,
    float* __restrict__ out) {
  extern __shared__ char smem[];
  float* zS    = (float*)(smem + L_ZS);     // [32][132]
  float* kS    = (float*)(smem + L_KS);     // [3][32][128]
  float* dxS   = (float*)(smem + L_DX);     // [32][16]
  _Float16* aHi  = (_Float16*)(smem + L_ACT);            // [32][136]
  _Float16* aLo  = (_Float16*)(smem + L_ACT + 8704);
  _Float16* h0Hi = (_Float16*)(smem + L_ACT + 2 * 8704);
  _Float16* h0Lo = (_Float16*)(smem + L_ACT + 3 * 8704);
  _Float16* h1Hi = (_Float16*)(smem + L_ACT + 4 * 8704);
  _Float16* h1Lo = (_Float16*)(smem + L_ACT + 5 * 8704);
  float* biasS = (float*)(smem + L_BIAS);   // [2624]

  const int tid = threadIdx.x;
  const int w = tid >> 6;
  const int lane = tid & 63;
  const int row = lane & 15;
  const int g = lane >> 4;
  const int gb0 = blockIdx.x * 32;

  // ---- bias staging
  for (int e = tid; e < 2624; e += 512) {
    float v;
    if (e < 128)       v = b0[e];
    else if (e < 512)  v = bl[e - 128];
    else if (e < 2560) v = bf[e - 512];
    else               v = b_last[e - 2560];
    biasS[e] = v;
  }
  // ---- z0 = x0 @ W_init^T + b_init
  for (int e = tid; e < 4096; e += 512) {
    int b = e >> 7, n = e & 127;
    const float* cr = coeffs + (size_t)(gb0 + b) * (31 * 64);  // t=0, 'a' block
    float s0 = b_init[n];
#pragma unroll
    for (int i = 0; i < 16; ++i) s0 += cr[i] * W_init[n * 16 + i];
    zS[b * 132 + n] = s0;
  }
  __syncthreads();

  out_gemm(0, gb0, w, row, g, zS, ws, biasS, out);

#pragma unroll 1
  for (int t = 0; t < 31; ++t) {
#pragma unroll 1
    for (int s = 0; s < 4; ++s) {
      // ---- dx (one entry per thread: 32x16 = 512)
      {
        int b = tid >> 4, i = tid & 15;
        const float* cr = coeffs + ((size_t)(gb0 + b) * 31 + t) * 64;
        float frac = (s == 3) ? 1.f : s * (1.f / 3.f);
        dxS[b * 16 + i] = cr[16 + i] + (cr[32 + i] + cr[48 + i] * frac) * frac;
      }
      // ---- zz = stage argument; on s==3 fold partial z-update (vectorized x4)
      for (int e = tid; e < 1024; e += 512) {
        int b = e >> 5;
        int c = (e & 31) * 4;
        float* zp = zS + b * 132 + c;
        f32x4 z = *(const f32x4*)zp;
        f32x4 v = z;
        if (s == 1) {
          f32x4 k1 = *(const f32x4*)(kS + b * 128 + c);
          v = z + k1 * (1.f / 3.f);
        } else if (s == 2) {
          f32x4 k1 = *(const f32x4*)(kS + b * 128 + c);
          f32x4 k2 = *(const f32x4*)(kS + (32 + b) * 128 + c);
          v = z + k2 - k1 * (1.f / 3.f);
        } else if (s == 3) {
          f32x4 k1 = *(const f32x4*)(kS + b * 128 + c);
          f32x4 k2 = *(const f32x4*)(kS + (32 + b) * 128 + c);
          f32x4 k3 = *(const f32x4*)(kS + (64 + b) * 128 + c);
          v = z + k1 - k2 + k3;
          *(f32x4*)zp = z + 0.125f * (k1 + 3.f * (k2 + k3));  // + k4/8 in G5
        }
        half4 hi, lo;
#pragma unroll
        for (int j = 0; j < 4; ++j) {
          _Float16 h = (_Float16)v[j];
          hi[j] = h;
          lo[j] = (_Float16)(v[j] - (float)h);
        }
        *(half4*)(aHi + b * 136 + c) = hi;
        *(half4*)(aLo + b * 136 + c) = lo;
      }
      __syncthreads();

      // ---- G1..G4
      hidden_layer_pair(aHi, aLo, h0Hi, h0Lo, ws + OFF_W0HI, ws + OFF_W0LO,
                        biasS, w, row, g);
      __syncthreads();
      hidden_layer_pair(h0Hi, h0Lo, h1Hi, h1Lo, ws + OFF_WL, ws + OFF_WL + 16384,
                        biasS + 128, w, row, g);
      __syncthreads();
      hidden_layer_pair(h1Hi, h1Lo, h0Hi, h0Lo, ws + OFF_WL + 32768,
                        ws + OFF_WL + 32768 + 16384, biasS + 256, w, row, g);
      __syncthreads();
      hidden_layer_pair(h0Hi, h0Lo, h1Hi, h1Lo, ws + OFF_WL + 65536,
                        ws + OFF_WL + 65536 + 16384, biasS + 384, w, row, g);
      __syncthreads();

      // ---- G5: f = tanh(h @ Wf^T + bf); k = einsum(f, dx). A-frags hoisted.
      half8 Ah0[4], Al0[4], Ah1[4], Al1[4];
#pragma unroll
      for (int kc = 0; kc < 4; ++kc) {
        Ah0[kc] = *(const half8*)(h1Hi + row * 136 + kc * 32 + g * 8);
        Al0[kc] = *(const half8*)(h1Lo + row * 136 + kc * 32 + g * 8);
        Ah1[kc] = *(const half8*)(h1Hi + (row + 16) * 136 + kc * 32 + g * 8);
        Al1[kc] = *(const half8*)(h1Lo + (row + 16) * 136 + kc * 32 + g * 8);
      }
      const int lane16 = g * 16 + row;
#pragma unroll 2
      for (int it = 0; it < 16; ++it) {
        int nt = w * 16 + it;  // = h index
        const _Float16* bhp = ws + OFF_WFHI + nt * 2048;
        const _Float16* blp = ws + OFF_WFLO + nt * 2048;
        f32x4 acc0 = {0.f, 0.f, 0.f, 0.f}, acc1 = {0.f, 0.f, 0.f, 0.f};
#pragma unroll
        for (int kc = 0; kc < 4; ++kc) {
          half8 bh = *(const half8*)(bhp + (kc * 64 + lane16) * 8);
          half8 bl = *(const half8*)(blp + (kc * 64 + lane16) * 8);
          acc0 = __builtin_amdgcn_mfma_f32_16x16x32_f16(Ah0[kc], bh, acc0, 0, 0, 0);
          acc1 = __builtin_amdgcn_mfma_f32_16x16x32_f16(Ah1[kc], bh, acc1, 0, 0, 0);
          acc0 = __builtin_amdgcn_mfma_f32_16x16x32_f16(Al0[kc], bh, acc0, 0, 0, 0);
          acc1 = __builtin_amdgcn_mfma_f32_16x16x32_f16(Al1[kc], bh, acc1, 0, 0, 0);
          acc0 = __builtin_amdgcn_mfma_f32_16x16x32_f16(Ah0[kc], bl, acc0, 0, 0, 0);
          acc1 = __builtin_amdgcn_mfma_f32_16x16x32_f16(Ah1[kc], bl, acc1, 0, 0, 0);
        }
        float bv = biasS[512 + nt * 16 + row];  // row = i (col of tile)
        float t0[4], t1[4];
#pragma unroll
        for (int r = 0; r < 4; ++r) {
          float x0 = acc0[r] + bv;
          float e0 = __expf(2.f * x0);               // inf-safe
          float th0 = 1.f - __fdividef(2.f, e0 + 1.f);
          t0[r] = th0 * dxS[(g * 4 + r) * 16 + row];
          float x1 = acc1[r] + bv;
          float e1 = __expf(2.f * x1);
          float th1 = 1.f - __fdividef(2.f, e1 + 1.f);
          t1[r] = th1 * dxS[(16 + g * 4 + r) * 16 + row];
        }
#pragma unroll
        for (int r = 0; r < 4; ++r) {
          t0[r] = swz_add<0x041F>(t0[r]); t1[r] = swz_add<0x041F>(t1[r]);
          t0[r] = swz_add<0x081F>(t0[r]); t1[r] = swz_add<0x081F>(t1[r]);
          t0[r] = swz_add<0x101F>(t0[r]); t1[r] = swz_add<0x101F>(t1[r]);
          t0[r] = swz_add<0x201F>(t0[r]); t1[r] = swz_add<0x201F>(t1[r]);
        }
        if (row == 0) {
#pragma unroll
          for (int r = 0; r < 4; ++r) {
            if (s < 3) {
              kS[(s * 32 + g * 4 + r) * 128 + nt] = t0[r];
              kS[(s * 32 + 16 + g * 4 + r) * 128 + nt] = t1[r];
            } else {
              zS[(g * 4 + r) * 132 + nt] += 0.125f * t0[r];
              zS[(16 + g * 4 + r) * 132 + nt] += 0.125f * t1[r];
            }
          }
        }
      }
      __syncthreads();
    }
    out_gemm(t + 1, gb0, w, row, g, zS, ws, biasS, out);
  }
}

extern "C" void kernel_launch(void* const* d_in, const int* in_sizes, int n_in,
                              void* d_out, int out_size, void* d_ws, size_t ws_size,
                              hipStream_t stream) {
  const float* coeffs = (const float*)d_in[1];
  const float* W_init = (const float*)d_in[2];
  const float* b_init = (const float*)d_in[3];
  const float* W0     = (const float*)d_in[4];
  const float* b0     = (const float*)d_in[5];
  const float* Wl     = (const float*)d_in[6];
  const float* bl     = (const float*)d_in[7];
  const float* Wf     = (const float*)d_in[8];
  const float* bf     = (const float*)d_in[9];
  const float* Wlast  = (const float*)d_in[10];
  const float* b_last = (const float*)d_in[11];
  _Float16* ws = (_Float16*)d_ws;
  float* out = (float*)d_out;

  (void)hipFuncSetAttribute((const void*)cde_kernel,
                            hipFuncAttributeMaxDynamicSharedMemorySize,
                            LDS_BYTES);
  prep_kernel<<<1312, 256, 0, stream>>>(W0, Wl, Wf, Wlast, ws);
  cde_kernel<<<8, 512, LDS_BYTES, stream>>>(coeffs, W_init, b_init, b0, bl, bf,
                                            b_last, ws, out);
}

// Round 3
// 1954.846 us; speedup vs baseline: 1.8184x; 1.8184x over previous
//
#include <hip/hip_runtime.h>

typedef _Float16 half8 __attribute__((ext_vector_type(8)));
typedef _Float16 half4 __attribute__((ext_vector_type(4)));
typedef float f32x4 __attribute__((ext_vector_type(4)));

// ---- ws layout (offsets in halves). All matrices have K=128 -> 4 k-chunks.
// frag layout: idx = (((nt*4 + kc)*64) + lane)*8 + j  ==  element index e itself.
constexpr int OFF_W0HI   = 0;        // 16384
constexpr int OFF_W0LO   = 16384;
constexpr int OFF_WL     = 32768;    // + m*32768 (hi), +16384 (lo), m=0..2
constexpr int OFF_WFHI   = 131072;   // 262144
constexpr int OFF_WFLO   = 393216;   // (unused by cde_kernel after R3)
constexpr int OFF_WLASTHI = 655360;  // 8192
constexpr int OFF_WLASTLO = 663552;  // total 671744 halves = 1.31 MB

__device__ __forceinline__ void cvt_elem(const float* __restrict__ W,
                                         _Float16* __restrict__ hi,
                                         _Float16* __restrict__ lo, int e) {
  int j  = e & 7;
  int l  = (e >> 3) & 63;
  int r  = e >> 9;
  int kc = r & 3;
  int nt = r >> 2;
  int row = nt * 16 + (l & 15);
  int col = kc * 32 + ((l >> 4) << 3) + j;
  float v = W[row * 128 + col];
  _Float16 h = (_Float16)v;
  hi[e] = h;
  lo[e] = (_Float16)(v - (float)h);
}

__global__ __launch_bounds__(256) void prep_kernel(const float* __restrict__ W0,
                                                   const float* __restrict__ Wl,
                                                   const float* __restrict__ Wf,
                                                   const float* __restrict__ Wlast,
                                                   _Float16* __restrict__ ws) {
  int e = blockIdx.x * 256 + threadIdx.x;
  if (e < 16384) {
    cvt_elem(W0, ws + OFF_W0HI, ws + OFF_W0LO, e);
  } else if (e < 65536) {
    int ee = e - 16384;
    int m = ee >> 14;
    ee &= 16383;
    cvt_elem(Wl + m * 16384, ws + OFF_WL + m * 32768,
             ws + OFF_WL + m * 32768 + 16384, ee);
  } else if (e < 327680) {
    cvt_elem(Wf, ws + OFF_WFHI, ws + OFF_WFLO, e - 65536);
  } else if (e < 335872) {
    cvt_elem(Wlast, ws + OFF_WLASTHI, ws + OFF_WLASTLO, e - 327680);
  }
}

template <int PAT>
__device__ __forceinline__ float swz_add(float v) {
  return v + __int_as_float(__builtin_amdgcn_ds_swizzle(__float_as_int(v), PAT));
}

// hidden layer: 3-MFMA hi/lo split (acc += Ahi*Bhi + Alo*Bhi + Ahi*Blo), K=128
__device__ __forceinline__ void hidden_layer(
    const _Float16* __restrict__ srcHi, const _Float16* __restrict__ srcLo,
    _Float16* __restrict__ dstHi, _Float16* __restrict__ dstLo,
    const _Float16* __restrict__ wHi, const _Float16* __restrict__ wLo,
    const float* __restrict__ bias, int w, int row, int g) {
  f32x4 acc = {0.f, 0.f, 0.f, 0.f};
  const int lane = g * 16 + row;
#pragma unroll
  for (int kc = 0; kc < 4; ++kc) {
    half8 bh = *(const half8*)(wHi + w * 2048 + (kc * 64 + lane) * 8);
    half8 bl = *(const half8*)(wLo + w * 2048 + (kc * 64 + lane) * 8);
    half8 ah = *(const half8*)(srcHi + row * 136 + kc * 32 + g * 8);
    half8 al = *(const half8*)(srcLo + row * 136 + kc * 32 + g * 8);
    acc = __builtin_amdgcn_mfma_f32_16x16x32_f16(ah, bh, acc, 0, 0, 0);
    acc = __builtin_amdgcn_mfma_f32_16x16x32_f16(al, bh, acc, 0, 0, 0);
    acc = __builtin_amdgcn_mfma_f32_16x16x32_f16(ah, bl, acc, 0, 0, 0);
  }
  int n = w * 16 + row;
  float bv = bias[n];
#pragma unroll
  for (int r = 0; r < 4; ++r) {
    float v = fmaxf(acc[r] + bv, 0.f);
    _Float16 h = (_Float16)v;
    dstHi[(g * 4 + r) * 136 + n] = h;
    dstLo[(g * 4 + r) * 136 + n] = (_Float16)(v - (float)h);
  }
}

__device__ __forceinline__ void out_gemm(int tt, int gb0, int w, int row, int g,
                                         const float* __restrict__ zS,
                                         const _Float16* __restrict__ ws,
                                         const float* __restrict__ biasS,
                                         float* __restrict__ out) {
  f32x4 acc = {0.f, 0.f, 0.f, 0.f};
  const int lane = g * 16 + row;
#pragma unroll
  for (int kc = 0; kc < 4; ++kc) {
    const float* zp = zS + row * 132 + kc * 32 + g * 8;
    f32x4 z0 = *(const f32x4*)zp;
    f32x4 z1 = *(const f32x4*)(zp + 4);
    half8 ah, al;
#pragma unroll
    for (int j = 0; j < 4; ++j) {
      _Float16 h = (_Float16)z0[j];
      ah[j] = h; al[j] = (_Float16)(z0[j] - (float)h);
      _Float16 h2 = (_Float16)z1[j];
      ah[4 + j] = h2; al[4 + j] = (_Float16)(z1[j] - (float)h2);
    }
    half8 bh = *(const half8*)(ws + OFF_WLASTHI + w * 2048 + (kc * 64 + lane) * 8);
    half8 bl = *(const half8*)(ws + OFF_WLASTLO + w * 2048 + (kc * 64 + lane) * 8);
    acc = __builtin_amdgcn_mfma_f32_16x16x32_f16(ah, bh, acc, 0, 0, 0);
    acc = __builtin_amdgcn_mfma_f32_16x16x32_f16(al, bh, acc, 0, 0, 0);
    acc = __builtin_amdgcn_mfma_f32_16x16x32_f16(ah, bl, acc, 0, 0, 0);
  }
  int o = w * 16 + row;
  float bv = biasS[2560 + o];
#pragma unroll
  for (int r = 0; r < 4; ++r) {
    float x = acc[r] + bv;
    float sg = __fdividef(1.f, 1.f + __expf(-x));
    out[((size_t)(gb0 + g * 4 + r) * 32 + tt) * 64 + o] = sg;
  }
}

__global__ __launch_bounds__(512) void cde_kernel(
    const float* __restrict__ coeffs, const float* __restrict__ W_init,
    const float* __restrict__ b_init, const float* __restrict__ b0,
    const float* __restrict__ bl, const float* __restrict__ bf,
    const float* __restrict__ b_last, const _Float16* __restrict__ ws,
    float* __restrict__ out) {
  __shared__ float zS[16 * 132];
  __shared__ float kS[3 * 16 * 128];
  __shared__ float dxS[16 * 16];
  // bufA: a / h1 (aliased); bufB: h0
  __shared__ _Float16 bufAHi[16 * 136], bufALo[16 * 136];
  __shared__ _Float16 bufBHi[16 * 136], bufBLo[16 * 136];
  __shared__ float biasS[2624];

  const int tid = threadIdx.x;
  const int w = tid >> 6;
  const int lane = tid & 63;
  const int row = lane & 15;
  const int g = lane >> 4;
  const int gb0 = blockIdx.x * 16;

  // ---- bias staging
  for (int e = tid; e < 2624; e += 512) {
    float v;
    if (e < 128)       v = b0[e];
    else if (e < 512)  v = bl[e - 128];
    else if (e < 2560) v = bf[e - 512];
    else               v = b_last[e - 2560];
    biasS[e] = v;
  }
  // ---- z0 = x0 @ W_init^T + b_init
  for (int e = tid; e < 2048; e += 512) {
    int b = e >> 7, n = e & 127;
    const float* cr = coeffs + (size_t)(gb0 + b) * (31 * 64);  // t=0, 'a' block
    float s0 = b_init[n];
#pragma unroll
    for (int i = 0; i < 16; ++i) s0 += cr[i] * W_init[n * 16 + i];
    zS[b * 132 + n] = s0;
  }
  __syncthreads();

  if (w < 4) out_gemm(0, gb0, w, row, g, zS, ws, biasS, out);

#pragma unroll 1
  for (int t = 0; t < 31; ++t) {
#pragma unroll 1
    for (int s = 0; s < 4; ++s) {
      // ---- dx: 16x16 = 256 entries
      if (tid < 256) {
        int b = tid >> 4, i = tid & 15;
        const float* cr = coeffs + ((size_t)(gb0 + b) * 31 + t) * 64;
        float frac = (s == 3) ? 1.f : s * (1.f / 3.f);
        dxS[b * 16 + i] = cr[16 + i] + (cr[32 + i] + cr[48 + i] * frac) * frac;
      }
      // ---- zz = stage argument (one f32x4 per thread: 16*32 = 512)
      {
        int b = tid >> 5;
        int c = (tid & 31) * 4;
        float* zp = zS + b * 132 + c;
        f32x4 z = *(const f32x4*)zp;
        f32x4 v = z;
        if (s == 1) {
          f32x4 k1 = *(const f32x4*)(kS + b * 128 + c);
          v = z + k1 * (1.f / 3.f);
        } else if (s == 2) {
          f32x4 k1 = *(const f32x4*)(kS + b * 128 + c);
          f32x4 k2 = *(const f32x4*)(kS + (16 + b) * 128 + c);
          v = z + k2 - k1 * (1.f / 3.f);
        } else if (s == 3) {
          f32x4 k1 = *(const f32x4*)(kS + b * 128 + c);
          f32x4 k2 = *(const f32x4*)(kS + (16 + b) * 128 + c);
          f32x4 k3 = *(const f32x4*)(kS + (32 + b) * 128 + c);
          v = z + k1 - k2 + k3;
          *(f32x4*)zp = z + 0.125f * (k1 + 3.f * (k2 + k3));  // + k4/8 in G5
        }
        half4 hi, lo;
#pragma unroll
        for (int j = 0; j < 4; ++j) {
          _Float16 h = (_Float16)v[j];
          hi[j] = h;
          lo[j] = (_Float16)(v[j] - (float)h);
        }
        *(half4*)(bufAHi + b * 136 + c) = hi;
        *(half4*)(bufALo + b * 136 + c) = lo;
      }
      __syncthreads();

      // ---- G1..G4 (bufA = a/h1, bufB = h0; a dead after G1)
      hidden_layer(bufAHi, bufALo, bufBHi, bufBLo, ws + OFF_W0HI, ws + OFF_W0LO,
                   biasS, w, row, g);
      __syncthreads();
      hidden_layer(bufBHi, bufBLo, bufAHi, bufALo, ws + OFF_WL,
                   ws + OFF_WL + 16384, biasS + 128, w, row, g);
      __syncthreads();
      hidden_layer(bufAHi, bufALo, bufBHi, bufBLo, ws + OFF_WL + 32768,
                   ws + OFF_WL + 32768 + 16384, biasS + 256, w, row, g);
      __syncthreads();
      hidden_layer(bufBHi, bufBLo, bufAHi, bufALo, ws + OFF_WL + 65536,
                   ws + OFF_WL + 65536 + 16384, biasS + 384, w, row, g);
      __syncthreads();

      // ---- G5: f = tanh(h @ Wf^T + bf); k = einsum(f, dx).
      // A-frags hoisted to regs; B = Wf-hi only (f16 weights; err ~1e-4/elem).
      half8 Ah[4], Al[4];
#pragma unroll
      for (int kc = 0; kc < 4; ++kc) {
        Ah[kc] = *(const half8*)(bufAHi + row * 136 + kc * 32 + g * 8);
        Al[kc] = *(const half8*)(bufALo + row * 136 + kc * 32 + g * 8);
      }
      const int lane16 = g * 16 + row;
#pragma unroll 2
      for (int it = 0; it < 16; ++it) {
        int nt = w * 16 + it;  // = h index
        const _Float16* bhp = ws + OFF_WFHI + nt * 2048;
        f32x4 acc = {0.f, 0.f, 0.f, 0.f};
#pragma unroll
        for (int kc = 0; kc < 4; ++kc) {
          half8 bh = *(const half8*)(bhp + (kc * 64 + lane16) * 8);
          acc = __builtin_amdgcn_mfma_f32_16x16x32_f16(Ah[kc], bh, acc, 0, 0, 0);
          acc = __builtin_amdgcn_mfma_f32_16x16x32_f16(Al[kc], bh, acc, 0, 0, 0);
        }
        float bv = biasS[512 + nt * 16 + row];  // row = i (col of tile)
        float ts[4];
#pragma unroll
        for (int r = 0; r < 4; ++r) {
          float x = acc[r] + bv;
          float e0 = __expf(2.f * x);               // inf-safe tanh
          float th = 1.f - __fdividef(2.f, e0 + 1.f);
          ts[r] = th * dxS[(g * 4 + r) * 16 + row];
        }
#pragma unroll
        for (int r = 0; r < 4; ++r) {
          ts[r] = swz_add<0x041F>(ts[r]);
          ts[r] = swz_add<0x081F>(ts[r]);
          ts[r] = swz_add<0x101F>(ts[r]);
          ts[r] = swz_add<0x201F>(ts[r]);
        }
        if (row == 0) {
#pragma unroll
          for (int r = 0; r < 4; ++r) {
            if (s < 3) kS[(s * 16 + g * 4 + r) * 128 + nt] = ts[r];
            else       zS[(g * 4 + r) * 132 + nt] += 0.125f * ts[r];
          }
        }
      }
      __syncthreads();
    }
    if (w < 4) out_gemm(t + 1, gb0, w, row, g, zS, ws, biasS, out);
  }
}

extern "C" void kernel_launch(void* const* d_in, const int* in_sizes, int n_in,
                              void* d_out, int out_size, void* d_ws, size_t ws_size,
                              hipStream_t stream) {
  const float* coeffs = (const float*)d_in[1];
  const float* W_init = (const float*)d_in[2];
  const float* b_init = (const float*)d_in[3];
  const float* W0     = (const float*)d_in[4];
  const float* b0     = (const float*)d_in[5];
  const float* bl     = (const float*)d_in[7];
  const float* Wl     = (const float*)d_in[6];
  const float* Wf     = (const float*)d_in[8];
  const float* bf     = (const float*)d_in[9];
  const float* Wlast  = (const float*)d_in[10];
  const float* b_last = (const float*)d_in[11];
  _Float16* ws = (_Float16*)d_ws;
  float* out = (float*)d_out;

  prep_kernel<<<1312, 256, 0, stream>>>(W0, Wl, Wf, Wlast, ws);
  cde_kernel<<<16, 512, 0, stream>>>(coeffs, W_init, b_init, b0, bl, bf, b_last,
                                     ws, out);
}

// Round 4
// 1494.633 us; speedup vs baseline: 2.3783x; 1.3079x over previous
//
#include <hip/hip_runtime.h>

typedef _Float16 half8 __attribute__((ext_vector_type(8)));
typedef _Float16 half4 __attribute__((ext_vector_type(4)));
typedef float f32x4 __attribute__((ext_vector_type(4)));

// ---- ws layout (offsets in halves). All matrices have K=128 -> 4 k-chunks.
// frag layout: idx = (((nt*4 + kc)*64) + lane)*8 + j  ==  element index e itself.
constexpr int OFF_W0HI   = 0;        // 16384
constexpr int OFF_W0LO   = 16384;
constexpr int OFF_WL     = 32768;    // + m*32768 (hi), +16384 (lo), m=0..2
constexpr int OFF_WFHI   = 131072;   // 262144
constexpr int OFF_WFLO   = 393216;   // (unused by cde_kernel)
constexpr int OFF_WLASTHI = 655360;  // 8192
constexpr int OFF_WLASTLO = 663552;  // total 671744 halves = 1.31 MB

__device__ __forceinline__ void cvt_elem(const float* __restrict__ W,
                                         _Float16* __restrict__ hi,
                                         _Float16* __restrict__ lo, int e) {
  int j  = e & 7;
  int l  = (e >> 3) & 63;
  int r  = e >> 9;
  int kc = r & 3;
  int nt = r >> 2;
  int row = nt * 16 + (l & 15);
  int col = kc * 32 + ((l >> 4) << 3) + j;
  float v = W[row * 128 + col];
  _Float16 h = (_Float16)v;
  hi[e] = h;
  lo[e] = (_Float16)(v - (float)h);
}

__global__ __launch_bounds__(256) void prep_kernel(const float* __restrict__ W0,
                                                   const float* __restrict__ Wl,
                                                   const float* __restrict__ Wf,
                                                   const float* __restrict__ Wlast,
                                                   _Float16* __restrict__ ws) {
  int e = blockIdx.x * 256 + threadIdx.x;
  if (e < 16384) {
    cvt_elem(W0, ws + OFF_W0HI, ws + OFF_W0LO, e);
  } else if (e < 65536) {
    int ee = e - 16384;
    int m = ee >> 14;
    ee &= 16383;
    cvt_elem(Wl + m * 16384, ws + OFF_WL + m * 32768,
             ws + OFF_WL + m * 32768 + 16384, ee);
  } else if (e < 327680) {
    cvt_elem(Wf, ws + OFF_WFHI, ws + OFF_WFLO, e - 65536);
  } else if (e < 335872) {
    cvt_elem(Wlast, ws + OFF_WLASTHI, ws + OFF_WLASTLO, e - 327680);
  }
}

// v += v shifted right by (CTRL-0x110) within each 16-lane row; 0-fill.
// After 1,2,4,8 chain, lane 15 of each row holds the 16-lane sum.
template <int CTRL>
__device__ __forceinline__ float dpp_red(float v) {
  int t = __builtin_amdgcn_update_dpp(0, __float_as_int(v), CTRL, 0xf, 0xf, true);
  return v + __int_as_float(t);
}

__device__ __forceinline__ void out_gemm(int tt, int gb0, int w, int row, int g,
                                         const float* __restrict__ zS,
                                         const _Float16* __restrict__ ws,
                                         const float* __restrict__ biasS,
                                         float* __restrict__ out) {
  f32x4 acc = {0.f, 0.f, 0.f, 0.f};
  const int lane = g * 16 + row;
#pragma unroll
  for (int kc = 0; kc < 4; ++kc) {
    const float* zp = zS + row * 132 + kc * 32 + g * 8;
    f32x4 z0 = *(const f32x4*)zp;
    f32x4 z1 = *(const f32x4*)(zp + 4);
    half8 ah, al;
#pragma unroll
    for (int j = 0; j < 4; ++j) {
      _Float16 h = (_Float16)z0[j];
      ah[j] = h; al[j] = (_Float16)(z0[j] - (float)h);
      _Float16 h2 = (_Float16)z1[j];
      ah[4 + j] = h2; al[4 + j] = (_Float16)(z1[j] - (float)h2);
    }
    half8 bh = *(const half8*)(ws + OFF_WLASTHI + w * 2048 + (kc * 64 + lane) * 8);
    half8 bl = *(const half8*)(ws + OFF_WLASTLO + w * 2048 + (kc * 64 + lane) * 8);
    acc = __builtin_amdgcn_mfma_f32_16x16x32_f16(ah, bh, acc, 0, 0, 0);
    acc = __builtin_amdgcn_mfma_f32_16x16x32_f16(al, bh, acc, 0, 0, 0);
    acc = __builtin_amdgcn_mfma_f32_16x16x32_f16(ah, bl, acc, 0, 0, 0);
  }
  int o = w * 16 + row;
  float bv = biasS[2560 + o];
#pragma unroll
  for (int r = 0; r < 4; ++r) {
    float x = acc[r] + bv;
    float sg = __fdividef(1.f, 1.f + __expf(-x));
    out[((size_t)(gb0 + g * 4 + r) * 32 + tt) * 64 + o] = sg;
  }
}

__global__ __launch_bounds__(512) void cde_kernel(
    const float* __restrict__ coeffs, const float* __restrict__ W_init,
    const float* __restrict__ b_init, const float* __restrict__ b0,
    const float* __restrict__ bl, const float* __restrict__ bf,
    const float* __restrict__ b_last, const _Float16* __restrict__ ws,
    float* __restrict__ out) {
  __shared__ float zS[16 * 132];
  __shared__ float kS[3 * 16 * 128];
  __shared__ float dxS[16 * 16];
  // bufA: a / h1 (aliased); bufB: h0
  __shared__ _Float16 bufAHi[16 * 136], bufALo[16 * 136];
  __shared__ _Float16 bufBHi[16 * 136], bufBLo[16 * 136];
  __shared__ float biasS[2624];

  const int tid = threadIdx.x;
  const int w = tid >> 6;
  const int lane = tid & 63;
  const int row = lane & 15;
  const int g = lane >> 4;
  const int gb0 = blockIdx.x * 16;

  // ---- bias staging
  for (int e = tid; e < 2624; e += 512) {
    float v;
    if (e < 128)       v = b0[e];
    else if (e < 512)  v = bl[e - 128];
    else if (e < 2560) v = bf[e - 512];
    else               v = b_last[e - 2560];
    biasS[e] = v;
  }
  // ---- z0 = x0 @ W_init^T + b_init
  for (int e = tid; e < 2048; e += 512) {
    int b = e >> 7, n = e & 127;
    const float* cr = coeffs + (size_t)(gb0 + b) * (31 * 64);  // t=0, 'a' block
    float s0 = b_init[n];
#pragma unroll
    for (int i = 0; i < 16; ++i) s0 += cr[i] * W_init[n * 16 + i];
    zS[b * 132 + n] = s0;
  }

  // ---- B-fragment prefetch register sets (double-buffered across layers)
  half8 pAh[4], pAl[4], pBh[4], pBl[4];
  auto loadB = [&](half8* bh, half8* blo, const _Float16* hi,
                   const _Float16* lo) {
#pragma unroll
    for (int kc = 0; kc < 4; ++kc) {
      bh[kc]  = *(const half8*)(hi + w * 2048 + (kc * 64 + lane) * 8);
      blo[kc] = *(const half8*)(lo + w * 2048 + (kc * 64 + lane) * 8);
    }
  };
  auto hiddenCompute = [&](const half8* bh, const half8* blo,
                           const _Float16* srcHi, const _Float16* srcLo,
                           _Float16* dstHi, _Float16* dstLo,
                           const float* bias, bool writeLo) {
    f32x4 acc = {0.f, 0.f, 0.f, 0.f};
#pragma unroll
    for (int kc = 0; kc < 4; ++kc) {
      half8 ah = *(const half8*)(srcHi + row * 136 + kc * 32 + g * 8);
      half8 al = *(const half8*)(srcLo + row * 136 + kc * 32 + g * 8);
      acc = __builtin_amdgcn_mfma_f32_16x16x32_f16(ah, bh[kc], acc, 0, 0, 0);
      acc = __builtin_amdgcn_mfma_f32_16x16x32_f16(al, bh[kc], acc, 0, 0, 0);
      acc = __builtin_amdgcn_mfma_f32_16x16x32_f16(ah, blo[kc], acc, 0, 0, 0);
    }
    int n = w * 16 + row;
    float bv = bias[n];
#pragma unroll
    for (int r = 0; r < 4; ++r) {
      float v = fmaxf(acc[r] + bv, 0.f);
      _Float16 h = (_Float16)v;
      dstHi[(g * 4 + r) * 136 + n] = h;
      if (writeLo) dstLo[(g * 4 + r) * 136 + n] = (_Float16)(v - (float)h);
    }
  };

  loadB(pAh, pAl, ws + OFF_W0HI, ws + OFF_W0LO);  // G1's B, in flight
  __syncthreads();

  if (w < 4) out_gemm(0, gb0, w, row, g, zS, ws, biasS, out);

#pragma unroll 1
  for (int t = 0; t < 31; ++t) {
#pragma unroll 1
    for (int s = 0; s < 4; ++s) {
      // ---- dx: 16x16 = 256 entries
      if (tid < 256) {
        int b = tid >> 4, i = tid & 15;
        const float* cr = coeffs + ((size_t)(gb0 + b) * 31 + t) * 64;
        float frac = (s == 3) ? 1.f : s * (1.f / 3.f);
        dxS[b * 16 + i] = cr[16 + i] + (cr[32 + i] + cr[48 + i] * frac) * frac;
      }
      // ---- zz = stage argument (one f32x4 per thread: 16*32 = 512)
      {
        int b = tid >> 5;
        int c = (tid & 31) * 4;
        float* zp = zS + b * 132 + c;
        f32x4 z = *(const f32x4*)zp;
        f32x4 v = z;
        if (s == 1) {
          f32x4 k1 = *(const f32x4*)(kS + b * 128 + c);
          v = z + k1 * (1.f / 3.f);
        } else if (s == 2) {
          f32x4 k1 = *(const f32x4*)(kS + b * 128 + c);
          f32x4 k2 = *(const f32x4*)(kS + (16 + b) * 128 + c);
          v = z + k2 - k1 * (1.f / 3.f);
        } else if (s == 3) {
          f32x4 k1 = *(const f32x4*)(kS + b * 128 + c);
          f32x4 k2 = *(const f32x4*)(kS + (16 + b) * 128 + c);
          f32x4 k3 = *(const f32x4*)(kS + (32 + b) * 128 + c);
          v = z + k1 - k2 + k3;
          *(f32x4*)zp = z + 0.125f * (k1 + 3.f * (k2 + k3));  // + k4/8 in G5
        }
        half4 hi, lo;
#pragma unroll
        for (int j = 0; j < 4; ++j) {
          _Float16 h = (_Float16)v[j];
          hi[j] = h;
          lo[j] = (_Float16)(v[j] - (float)h);
        }
        *(half4*)(bufAHi + b * 136 + c) = hi;
        *(half4*)(bufALo + b * 136 + c) = lo;
      }
      __syncthreads();

      // ---- G1..G4, software-pipelined B prefetch (pA/pB reg sets alternate)
      loadB(pBh, pBl, ws + OFF_WL, ws + OFF_WL + 16384);            // G2's B
      hiddenCompute(pAh, pAl, bufAHi, bufALo, bufBHi, bufBLo, biasS, true);
      __syncthreads();
      loadB(pAh, pAl, ws + OFF_WL + 32768, ws + OFF_WL + 32768 + 16384);  // G3
      hiddenCompute(pBh, pBl, bufBHi, bufBLo, bufAHi, bufALo, biasS + 128, true);
      __syncthreads();
      loadB(pBh, pBl, ws + OFF_WL + 65536, ws + OFF_WL + 65536 + 16384);  // G4
      hiddenCompute(pAh, pAl, bufAHi, bufALo, bufBHi, bufBLo, biasS + 256, true);
      __syncthreads();
      hiddenCompute(pBh, pBl, bufBHi, bufBLo, bufAHi, bufALo, biasS + 384, false);
      __syncthreads();

      // ---- G5: f = tanh(h @ Wf^T + bf); k = einsum(f, dx).
      // A hi-only (f16), Wf hi-only. dx hoisted. DPP 16-lane reduce.
      float dxr[4];
#pragma unroll
      for (int r = 0; r < 4; ++r) dxr[r] = dxS[(g * 4 + r) * 16 + row];
      half8 Ah[4];
#pragma unroll
      for (int kc = 0; kc < 4; ++kc)
        Ah[kc] = *(const half8*)(bufAHi + row * 136 + kc * 32 + g * 8);
#pragma unroll 4
      for (int it = 0; it < 16; ++it) {
        int nt = w * 16 + it;  // = h index
        const _Float16* bhp = ws + OFF_WFHI + nt * 2048;
        f32x4 acc = {0.f, 0.f, 0.f, 0.f};
#pragma unroll
        for (int kc = 0; kc < 4; ++kc) {
          half8 bh = *(const half8*)(bhp + (kc * 64 + lane) * 8);
          acc = __builtin_amdgcn_mfma_f32_16x16x32_f16(Ah[kc], bh, acc, 0, 0, 0);
        }
        float bv = biasS[512 + nt * 16 + row];  // row = i (col of tile)
        float ts[4];
#pragma unroll
        for (int r = 0; r < 4; ++r) {
          float x = acc[r] + bv;
          float e0 = __expf(2.f * x);               // inf-safe tanh
          float th = 1.f - __fdividef(2.f, e0 + 1.f);
          ts[r] = th * dxr[r];
        }
#pragma unroll
        for (int r = 0; r < 4; ++r) {
          ts[r] = dpp_red<0x111>(ts[r]);   // row_shr:1
          ts[r] = dpp_red<0x112>(ts[r]);   // row_shr:2
          ts[r] = dpp_red<0x114>(ts[r]);   // row_shr:4
          ts[r] = dpp_red<0x118>(ts[r]);   // row_shr:8 -> lane15 = sum
        }
        if (row == 15) {
#pragma unroll
          for (int r = 0; r < 4; ++r) {
            if (s < 3) kS[(s * 16 + g * 4 + r) * 128 + nt] = ts[r];
            else       zS[(g * 4 + r) * 132 + nt] += 0.125f * ts[r];
          }
        }
      }
      // next stage's G1 B (W0): in flight through barrier + zz-prep
      loadB(pAh, pAl, ws + OFF_W0HI, ws + OFF_W0LO);
      __syncthreads();
    }
    if (w < 4) out_gemm(t + 1, gb0, w, row, g, zS, ws, biasS, out);
  }
}

extern "C" void kernel_launch(void* const* d_in, const int* in_sizes, int n_in,
                              void* d_out, int out_size, void* d_ws, size_t ws_size,
                              hipStream_t stream) {
  const float* coeffs = (const float*)d_in[1];
  const float* W_init = (const float*)d_in[2];
  const float* b_init = (const float*)d_in[3];
  const float* W0     = (const float*)d_in[4];
  const float* b0     = (const float*)d_in[5];
  const float* Wl     = (const float*)d_in[6];
  const float* bl     = (const float*)d_in[7];
  const float* Wf     = (const float*)d_in[8];
  const float* bf     = (const float*)d_in[9];
  const float* Wlast  = (const float*)d_in[10];
  const float* b_last = (const float*)d_in[11];
  _Float16* ws = (_Float16*)d_ws;
  float* out = (float*)d_out;

  prep_kernel<<<1312, 256, 0, stream>>>(W0, Wl, Wf, Wlast, ws);
  cde_kernel<<<16, 512, 0, stream>>>(coeffs, W_init, b_init, b0, bl, bf, b_last,
                                     ws, out);
}

// Round 5
// 1463.930 us; speedup vs baseline: 2.4282x; 1.0210x over previous
//
#include <hip/hip_runtime.h>

typedef _Float16 half8 __attribute__((ext_vector_type(8)));
typedef _Float16 half4 __attribute__((ext_vector_type(4)));
typedef float f32x4 __attribute__((ext_vector_type(4)));

// ---- ws layout (offsets in halves). All matrices have K=128 -> 4 k-chunks.
// frag layout: idx = (((nt*4 + kc)*64) + lane)*8 + j  ==  element index e itself.
constexpr int OFF_W0HI   = 0;        // 16384
constexpr int OFF_W0LO   = 16384;
constexpr int OFF_WL     = 32768;    // + m*32768 (hi), +16384 (lo), m=0..2
constexpr int OFF_WFHI   = 131072;   // 262144
constexpr int OFF_WFLO   = 393216;   // (unused by cde_kernel)
constexpr int OFF_WLASTHI = 655360;  // 8192
constexpr int OFF_WLASTLO = 663552;  // total 671744 halves = 1.31 MB

__device__ __forceinline__ void cvt_elem(const float* __restrict__ W,
                                         _Float16* __restrict__ hi,
                                         _Float16* __restrict__ lo, int e) {
  int j  = e & 7;
  int l  = (e >> 3) & 63;
  int r  = e >> 9;
  int kc = r & 3;
  int nt = r >> 2;
  int row = nt * 16 + (l & 15);
  int col = kc * 32 + ((l >> 4) << 3) + j;
  float v = W[row * 128 + col];
  _Float16 h = (_Float16)v;
  hi[e] = h;
  lo[e] = (_Float16)(v - (float)h);
}

__global__ __launch_bounds__(256) void prep_kernel(const float* __restrict__ W0,
                                                   const float* __restrict__ Wl,
                                                   const float* __restrict__ Wf,
                                                   const float* __restrict__ Wlast,
                                                   _Float16* __restrict__ ws) {
  int e = blockIdx.x * 256 + threadIdx.x;
  if (e < 16384) {
    cvt_elem(W0, ws + OFF_W0HI, ws + OFF_W0LO, e);
  } else if (e < 65536) {
    int ee = e - 16384;
    int m = ee >> 14;
    ee &= 16383;
    cvt_elem(Wl + m * 16384, ws + OFF_WL + m * 32768,
             ws + OFF_WL + m * 32768 + 16384, ee);
  } else if (e < 327680) {
    cvt_elem(Wf, ws + OFF_WFHI, ws + OFF_WFLO, e - 65536);
  } else if (e < 335872) {
    cvt_elem(Wlast, ws + OFF_WLASTHI, ws + OFF_WLASTLO, e - 327680);
  }
}

// v += v shifted right by (CTRL-0x110) within each 16-lane row; 0-fill.
// After 1,2,4,8 chain, lane 15 of each row holds the 16-lane sum.
template <int CTRL>
__device__ __forceinline__ float dpp_red(float v) {
  int t = __builtin_amdgcn_update_dpp(0, __float_as_int(v), CTRL, 0xf, 0xf, true);
  return v + __int_as_float(t);
}

__device__ __forceinline__ void out_gemm(int tt, int gb0, int w, int row, int g,
                                         const float* __restrict__ zS,
                                         const _Float16* __restrict__ ws,
                                         const float* __restrict__ biasS,
                                         float* __restrict__ out) {
  f32x4 acc = {0.f, 0.f, 0.f, 0.f};
  const int lane = g * 16 + row;
#pragma unroll
  for (int kc = 0; kc < 4; ++kc) {
    const float* zp = zS + row * 132 + kc * 32 + g * 8;
    f32x4 z0 = *(const f32x4*)zp;
    f32x4 z1 = *(const f32x4*)(zp + 4);
    half8 ah, al;
#pragma unroll
    for (int j = 0; j < 4; ++j) {
      _Float16 h = (_Float16)z0[j];
      ah[j] = h; al[j] = (_Float16)(z0[j] - (float)h);
      _Float16 h2 = (_Float16)z1[j];
      ah[4 + j] = h2; al[4 + j] = (_Float16)(z1[j] - (float)h2);
    }
    half8 bh = *(const half8*)(ws + OFF_WLASTHI + w * 2048 + (kc * 64 + lane) * 8);
    half8 bl = *(const half8*)(ws + OFF_WLASTLO + w * 2048 + (kc * 64 + lane) * 8);
    acc = __builtin_amdgcn_mfma_f32_16x16x32_f16(ah, bh, acc, 0, 0, 0);
    acc = __builtin_amdgcn_mfma_f32_16x16x32_f16(al, bh, acc, 0, 0, 0);
    acc = __builtin_amdgcn_mfma_f32_16x16x32_f16(ah, bl, acc, 0, 0, 0);
  }
  int o = w * 16 + row;
  float bv = biasS[2560 + o];
#pragma unroll
  for (int r = 0; r < 4; ++r) {
    float x = acc[r] + bv;
    float sg = __fdividef(1.f, 1.f + __expf(-x));
    out[((size_t)(gb0 + g * 4 + r) * 32 + tt) * 64 + o] = sg;
  }
}

__global__ __launch_bounds__(512) void cde_kernel(
    const float* __restrict__ coeffs, const float* __restrict__ W_init,
    const float* __restrict__ b_init, const float* __restrict__ b0,
    const float* __restrict__ bl, const float* __restrict__ bf,
    const float* __restrict__ b_last, const _Float16* __restrict__ ws,
    float* __restrict__ out) {
  __shared__ float zS[16 * 132];
  __shared__ float kS[3 * 16 * 128];
  __shared__ float dxS[16 * 16];
  // bufA: a / h1 (aliased); bufB: h0
  __shared__ _Float16 bufAHi[16 * 136], bufALo[16 * 136];
  __shared__ _Float16 bufBHi[16 * 136], bufBLo[16 * 136];
  __shared__ float biasS[2624];

  const int tid = threadIdx.x;
  const int w = tid >> 6;
  const int lane = tid & 63;
  const int row = lane & 15;
  const int g = lane >> 4;
  const int gb0 = blockIdx.x * 16;

  // ---- bias staging
  for (int e = tid; e < 2624; e += 512) {
    float v;
    if (e < 128)       v = b0[e];
    else if (e < 512)  v = bl[e - 128];
    else if (e < 2560) v = bf[e - 512];
    else               v = b_last[e - 2560];
    biasS[e] = v;
  }
  // ---- z0 = x0 @ W_init^T + b_init
  for (int e = tid; e < 2048; e += 512) {
    int b = e >> 7, n = e & 127;
    const float* cr = coeffs + (size_t)(gb0 + b) * (31 * 64);  // t=0, 'a' block
    float s0 = b_init[n];
#pragma unroll
    for (int i = 0; i < 16; ++i) s0 += cr[i] * W_init[n * 16 + i];
    zS[b * 132 + n] = s0;
  }

  // ---- persistent hidden-layer weights: each wave's 16-col slice, hi+lo.
  // 4 layers x 8 half8 = 128 VGPRs, loaded once, zero loads in the t-loop.
  half8 w0h[4], w0l[4], w1h[4], w1l[4], w2h[4], w2l[4], w3h[4], w3l[4];
  {
    auto loadBreg = [&](half8* bh, half8* blo, const _Float16* hi,
                        const _Float16* lo) {
#pragma unroll
      for (int kc = 0; kc < 4; ++kc) {
        bh[kc]  = *(const half8*)(hi + w * 2048 + (kc * 64 + lane) * 8);
        blo[kc] = *(const half8*)(lo + w * 2048 + (kc * 64 + lane) * 8);
      }
    };
    loadBreg(w0h, w0l, ws + OFF_W0HI, ws + OFF_W0LO);
    loadBreg(w1h, w1l, ws + OFF_WL, ws + OFF_WL + 16384);
    loadBreg(w2h, w2l, ws + OFF_WL + 32768, ws + OFF_WL + 32768 + 16384);
    loadBreg(w3h, w3l, ws + OFF_WL + 65536, ws + OFF_WL + 65536 + 16384);
  }

  // hidden layer: 3 independent MFMA chains (hh, lh, hl) for ILP, summed after
  auto hiddenCompute = [&](const half8* bh, const half8* blo,
                           const _Float16* srcHi, const _Float16* srcLo,
                           _Float16* dstHi, _Float16* dstLo,
                           const float* bias, bool writeLo) {
    f32x4 a0 = {0.f, 0.f, 0.f, 0.f};
    f32x4 a1 = {0.f, 0.f, 0.f, 0.f};
    f32x4 a2 = {0.f, 0.f, 0.f, 0.f};
#pragma unroll
    for (int kc = 0; kc < 4; ++kc) {
      half8 ah = *(const half8*)(srcHi + row * 136 + kc * 32 + g * 8);
      half8 al = *(const half8*)(srcLo + row * 136 + kc * 32 + g * 8);
      a0 = __builtin_amdgcn_mfma_f32_16x16x32_f16(ah, bh[kc], a0, 0, 0, 0);
      a1 = __builtin_amdgcn_mfma_f32_16x16x32_f16(al, bh[kc], a1, 0, 0, 0);
      a2 = __builtin_amdgcn_mfma_f32_16x16x32_f16(ah, blo[kc], a2, 0, 0, 0);
    }
    f32x4 acc = (a0 + a1) + a2;
    int n = w * 16 + row;
    float bv = bias[n];
#pragma unroll
    for (int r = 0; r < 4; ++r) {
      float v = fmaxf(acc[r] + bv, 0.f);
      _Float16 h = (_Float16)v;
      dstHi[(g * 4 + r) * 136 + n] = h;
      if (writeLo) dstLo[(g * 4 + r) * 136 + n] = (_Float16)(v - (float)h);
    }
  };

  __syncthreads();

  if (w < 4) out_gemm(0, gb0, w, row, g, zS, ws, biasS, out);

#pragma unroll 1
  for (int t = 0; t < 31; ++t) {
#pragma unroll 1
    for (int s = 0; s < 4; ++s) {
      // ---- dx: 16x16 = 256 entries
      if (tid < 256) {
        int b = tid >> 4, i = tid & 15;
        const float* cr = coeffs + ((size_t)(gb0 + b) * 31 + t) * 64;
        float frac = (s == 3) ? 1.f : s * (1.f / 3.f);
        dxS[b * 16 + i] = cr[16 + i] + (cr[32 + i] + cr[48 + i] * frac) * frac;
      }
      // ---- zz = stage argument (one f32x4 per thread: 16*32 = 512)
      {
        int b = tid >> 5;
        int c = (tid & 31) * 4;
        float* zp = zS + b * 132 + c;
        f32x4 z = *(const f32x4*)zp;
        f32x4 v = z;
        if (s == 1) {
          f32x4 k1 = *(const f32x4*)(kS + b * 128 + c);
          v = z + k1 * (1.f / 3.f);
        } else if (s == 2) {
          f32x4 k1 = *(const f32x4*)(kS + b * 128 + c);
          f32x4 k2 = *(const f32x4*)(kS + (16 + b) * 128 + c);
          v = z + k2 - k1 * (1.f / 3.f);
        } else if (s == 3) {
          f32x4 k1 = *(const f32x4*)(kS + b * 128 + c);
          f32x4 k2 = *(const f32x4*)(kS + (16 + b) * 128 + c);
          f32x4 k3 = *(const f32x4*)(kS + (32 + b) * 128 + c);
          v = z + k1 - k2 + k3;
          *(f32x4*)zp = z + 0.125f * (k1 + 3.f * (k2 + k3));  // + k4/8 in G5
        }
        half4 hi, lo;
#pragma unroll
        for (int j = 0; j < 4; ++j) {
          _Float16 h = (_Float16)v[j];
          hi[j] = h;
          lo[j] = (_Float16)(v[j] - (float)h);
        }
        *(half4*)(bufAHi + b * 136 + c) = hi;
        *(half4*)(bufALo + b * 136 + c) = lo;
      }
      __syncthreads();

      // ---- G1..G4: zero global loads (weights resident in VGPRs)
      hiddenCompute(w0h, w0l, bufAHi, bufALo, bufBHi, bufBLo, biasS, true);
      __syncthreads();
      hiddenCompute(w1h, w1l, bufBHi, bufBLo, bufAHi, bufALo, biasS + 128, true);
      __syncthreads();
      hiddenCompute(w2h, w2l, bufAHi, bufALo, bufBHi, bufBLo, biasS + 256, true);
      __syncthreads();
      hiddenCompute(w3h, w3l, bufBHi, bufBLo, bufAHi, bufALo, biasS + 384, false);
      __syncthreads();

      // ---- G5: f = tanh(h @ Wf^T + bf); k = einsum(f, dx).
      // A hi-only (f16), Wf hi-only (the sole remaining load stream).
      float dxr[4], dx2[4];
#pragma unroll
      for (int r = 0; r < 4; ++r) {
        dxr[r] = dxS[(g * 4 + r) * 16 + row];
        dx2[r] = dxr[r] + dxr[r];
      }
      half8 Ah[4];
#pragma unroll
      for (int kc = 0; kc < 4; ++kc)
        Ah[kc] = *(const half8*)(bufAHi + row * 136 + kc * 32 + g * 8);
#pragma unroll 4
      for (int it = 0; it < 16; ++it) {
        int nt = w * 16 + it;  // = h index
        const _Float16* bhp = ws + OFF_WFHI + nt * 2048;
        f32x4 acc = {0.f, 0.f, 0.f, 0.f};
#pragma unroll
        for (int kc = 0; kc < 4; ++kc) {
          half8 bh = *(const half8*)(bhp + (kc * 64 + lane) * 8);
          acc = __builtin_amdgcn_mfma_f32_16x16x32_f16(Ah[kc], bh, acc, 0, 0, 0);
        }
        float bv = biasS[512 + nt * 16 + row];  // row = i (col of tile)
        float ts[4];
#pragma unroll
        for (int r = 0; r < 4; ++r) {
          float x = acc[r] + bv;
          // tanh(x)*dx = dx - 2*dx / (exp(2x)+1); inf-safe at both ends
          float e2 = __expf(x + x);
          ts[r] = dxr[r] - __fdividef(dx2[r], e2 + 1.f);
        }
#pragma unroll
        for (int r = 0; r < 4; ++r) {
          ts[r] = dpp_red<0x111>(ts[r]);   // row_shr:1
          ts[r] = dpp_red<0x112>(ts[r]);   // row_shr:2
          ts[r] = dpp_red<0x114>(ts[r]);   // row_shr:4
          ts[r] = dpp_red<0x118>(ts[r]);   // row_shr:8 -> lane15 = sum
        }
        if (row == 15) {
#pragma unroll
          for (int r = 0; r < 4; ++r) {
            if (s < 3) kS[(s * 16 + g * 4 + r) * 128 + nt] = ts[r];
            else       zS[(g * 4 + r) * 132 + nt] += 0.125f * ts[r];
          }
        }
      }
      __syncthreads();
    }
    if (w < 4) out_gemm(t + 1, gb0, w, row, g, zS, ws, biasS, out);
  }
}

extern "C" void kernel_launch(void* const* d_in, const int* in_sizes, int n_in,
                              void* d_out, int out_size, void* d_ws, size_t ws_size,
                              hipStream_t stream) {
  const float* coeffs = (const float*)d_in[1];
  const float* W_init = (const float*)d_in[2];
  const float* b_init = (const float*)d_in[3];
  const float* W0     = (const float*)d_in[4];
  const float* b0     = (const float*)d_in[5];
  const float* Wl     = (const float*)d_in[6];
  const float* bl     = (const float*)d_in[7];
  const float* Wf     = (const float*)d_in[8];
  const float* bf     = (const float*)d_in[9];
  const float* Wlast  = (const float*)d_in[10];
  const float* b_last = (const float*)d_in[11];
  _Float16* ws = (_Float16*)d_ws;
  float* out = (float*)d_out;

  prep_kernel<<<1312, 256, 0, stream>>>(W0, Wl, Wf, Wlast, ws);
  cde_kernel<<<16, 512, 0, stream>>>(coeffs, W_init, b_init, b0, bl, bf, b_last,
                                     ws, out);
}

// Round 6
// 1304.201 us; speedup vs baseline: 2.7256x; 1.1225x over previous
//
#include <hip/hip_runtime.h>

typedef _Float16 half8 __attribute__((ext_vector_type(8)));
typedef _Float16 half4 __attribute__((ext_vector_type(4)));
typedef float f32x4 __attribute__((ext_vector_type(4)));

// ---- ws layout (offsets in halves). All matrices have K=128 -> 4 k-chunks.
// frag layout: idx = (((nt*4 + kc)*64) + lane)*8 + j  ==  element index e itself.
constexpr int OFF_W0HI   = 0;        // 16384
constexpr int OFF_W0LO   = 16384;
constexpr int OFF_WL     = 32768;    // + m*32768 (hi), +16384 (lo), m=0..2
constexpr int OFF_WFHI   = 131072;   // 262144
constexpr int OFF_WFLO   = 393216;   // (unused by cde_kernel)
constexpr int OFF_WLASTHI = 655360;  // 8192
constexpr int OFF_WLASTLO = 663552;  // total 671744 halves = 1.31 MB

__device__ __forceinline__ void cvt_elem(const float* __restrict__ W,
                                         _Float16* __restrict__ hi,
                                         _Float16* __restrict__ lo, int e) {
  int j  = e & 7;
  int l  = (e >> 3) & 63;
  int r  = e >> 9;
  int kc = r & 3;
  int nt = r >> 2;
  int row = nt * 16 + (l & 15);
  int col = kc * 32 + ((l >> 4) << 3) + j;
  float v = W[row * 128 + col];
  _Float16 h = (_Float16)v;
  hi[e] = h;
  lo[e] = (_Float16)(v - (float)h);
}

__global__ __launch_bounds__(256) void prep_kernel(const float* __restrict__ W0,
                                                   const float* __restrict__ Wl,
                                                   const float* __restrict__ Wf,
                                                   const float* __restrict__ Wlast,
                                                   _Float16* __restrict__ ws) {
  int e = blockIdx.x * 256 + threadIdx.x;
  if (e < 16384) {
    cvt_elem(W0, ws + OFF_W0HI, ws + OFF_W0LO, e);
  } else if (e < 65536) {
    int ee = e - 16384;
    int m = ee >> 14;
    ee &= 16383;
    cvt_elem(Wl + m * 16384, ws + OFF_WL + m * 32768,
             ws + OFF_WL + m * 32768 + 16384, ee);
  } else if (e < 327680) {
    cvt_elem(Wf, ws + OFF_WFHI, ws + OFF_WFLO, e - 65536);
  } else if (e < 335872) {
    cvt_elem(Wlast, ws + OFF_WLASTHI, ws + OFF_WLASTLO, e - 327680);
  }
}

// v += v shifted right by (CTRL-0x110) within each 16-lane row; 0-fill.
// After 1,2,4,8 chain, lane 15 of each row holds the 16-lane sum.
template <int CTRL>
__device__ __forceinline__ float dpp_red(float v) {
  int t = __builtin_amdgcn_update_dpp(0, __float_as_int(v), CTRL, 0xf, 0xf, true);
  return v + __int_as_float(t);
}

__device__ __forceinline__ void out_gemm(int tt, int gb0, int w, int row, int g,
                                         const float* __restrict__ zS,
                                         const _Float16* __restrict__ ws,
                                         const float* __restrict__ biasS,
                                         float* __restrict__ out) {
  f32x4 acc = {0.f, 0.f, 0.f, 0.f};
  const int lane = g * 16 + row;
#pragma unroll
  for (int kc = 0; kc < 4; ++kc) {
    const float* zp = zS + row * 132 + kc * 32 + g * 8;
    f32x4 z0 = *(const f32x4*)zp;
    f32x4 z1 = *(const f32x4*)(zp + 4);
    half8 ah, al;
#pragma unroll
    for (int j = 0; j < 4; ++j) {
      _Float16 h = (_Float16)z0[j];
      ah[j] = h; al[j] = (_Float16)(z0[j] - (float)h);
      _Float16 h2 = (_Float16)z1[j];
      ah[4 + j] = h2; al[4 + j] = (_Float16)(z1[j] - (float)h2);
    }
    half8 bh = *(const half8*)(ws + OFF_WLASTHI + w * 2048 + (kc * 64 + lane) * 8);
    half8 bl = *(const half8*)(ws + OFF_WLASTLO + w * 2048 + (kc * 64 + lane) * 8);
    acc = __builtin_amdgcn_mfma_f32_16x16x32_f16(ah, bh, acc, 0, 0, 0);
    acc = __builtin_amdgcn_mfma_f32_16x16x32_f16(al, bh, acc, 0, 0, 0);
    acc = __builtin_amdgcn_mfma_f32_16x16x32_f16(ah, bl, acc, 0, 0, 0);
  }
  int o = w * 16 + row;
  float bv = biasS[2560 + o];
#pragma unroll
  for (int r = 0; r < 4; ++r) {
    float x = acc[r] + bv;
    float sg = __fdividef(1.f, 1.f + __expf(-x));
    out[((size_t)(gb0 + g * 4 + r) * 32 + tt) * 64 + o] = sg;
  }
}

__global__ __launch_bounds__(512) void cde_kernel(
    const float* __restrict__ coeffs, const float* __restrict__ W_init,
    const float* __restrict__ b_init, const float* __restrict__ b0,
    const float* __restrict__ bl, const float* __restrict__ bf,
    const float* __restrict__ b_last, const _Float16* __restrict__ ws,
    float* __restrict__ out) {
  __shared__ float zS[16 * 132];
  __shared__ float kS[3 * 16 * 128];
  __shared__ float dxS[16 * 16];
  // bufA: a / h1 (aliased, hi + lo[G1 input only]); bufB: h0 (hi only)
  __shared__ _Float16 bufAHi[16 * 136], bufALo[16 * 136];
  __shared__ _Float16 bufBHi[16 * 136];
  __shared__ float biasS[2624];

  const int tid = threadIdx.x;
  const int w = tid >> 6;
  const int lane = tid & 63;
  const int row = lane & 15;
  const int g = lane >> 4;
  const int gb0 = blockIdx.x * 16;

  // ---- bias staging
  for (int e = tid; e < 2624; e += 512) {
    float v;
    if (e < 128)       v = b0[e];
    else if (e < 512)  v = bl[e - 128];
    else if (e < 2560) v = bf[e - 512];
    else               v = b_last[e - 2560];
    biasS[e] = v;
  }
  // ---- z0 = x0 @ W_init^T + b_init
  for (int e = tid; e < 2048; e += 512) {
    int b = e >> 7, n = e & 127;
    const float* cr = coeffs + (size_t)(gb0 + b) * (31 * 64);  // t=0, 'a' block
    float s0 = b_init[n];
#pragma unroll
    for (int i = 0; i < 16; ++i) s0 += cr[i] * W_init[n * 16 + i];
    zS[b * 132 + n] = s0;
  }

  // ---- persistent hidden-layer weights: each wave's 16-col slice, hi+lo.
  // 4 layers x 8 half8 = 128 VGPRs. asm-pinned so the compiler cannot
  // rematerialize the loads inside the loop (R5 failure mode: VGPR=120).
  half8 w0h[4], w0l[4], w1h[4], w1l[4], w2h[4], w2l[4], w3h[4], w3l[4];
  {
    auto loadBreg = [&](half8* bh, half8* blo, const _Float16* hi,
                        const _Float16* lo) {
#pragma unroll
      for (int kc = 0; kc < 4; ++kc) {
        bh[kc]  = *(const half8*)(hi + w * 2048 + (kc * 64 + lane) * 8);
        blo[kc] = *(const half8*)(lo + w * 2048 + (kc * 64 + lane) * 8);
      }
    };
    loadBreg(w0h, w0l, ws + OFF_W0HI, ws + OFF_W0LO);
    loadBreg(w1h, w1l, ws + OFF_WL, ws + OFF_WL + 16384);
    loadBreg(w2h, w2l, ws + OFF_WL + 32768, ws + OFF_WL + 32768 + 16384);
    loadBreg(w3h, w3l, ws + OFF_WL + 65536, ws + OFF_WL + 65536 + 16384);
#pragma unroll
    for (int kc = 0; kc < 4; ++kc) {
      asm volatile("" : "+v"(w0h[kc]), "+v"(w0l[kc]), "+v"(w1h[kc]), "+v"(w1l[kc]));
      asm volatile("" : "+v"(w2h[kc]), "+v"(w2l[kc]), "+v"(w3h[kc]), "+v"(w3l[kc]));
    }
  }

  // G1: full 3-chain hi/lo (z input has large magnitude)
  auto hiddenG1 = [&](const half8* bh, const half8* blo, _Float16* dstHi,
                      const float* bias) {
    f32x4 a0 = {0.f, 0.f, 0.f, 0.f};
    f32x4 a1 = {0.f, 0.f, 0.f, 0.f};
    f32x4 a2 = {0.f, 0.f, 0.f, 0.f};
#pragma unroll
    for (int kc = 0; kc < 4; ++kc) {
      half8 ah = *(const half8*)(bufAHi + row * 136 + kc * 32 + g * 8);
      half8 al = *(const half8*)(bufALo + row * 136 + kc * 32 + g * 8);
      a0 = __builtin_amdgcn_mfma_f32_16x16x32_f16(ah, bh[kc], a0, 0, 0, 0);
      a1 = __builtin_amdgcn_mfma_f32_16x16x32_f16(al, bh[kc], a1, 0, 0, 0);
      a2 = __builtin_amdgcn_mfma_f32_16x16x32_f16(ah, blo[kc], a2, 0, 0, 0);
    }
    f32x4 acc = (a0 + a1) + a2;
    int n = w * 16 + row;
    float bv = bias[n];
#pragma unroll
    for (int r = 0; r < 4; ++r) {
      float v = fmaxf(acc[r] + bv, 0.f);
      dstHi[(g * 4 + r) * 136 + n] = (_Float16)v;
    }
  };
  // G2..G4: act-hi only (ReLU outputs small; rel err 2.4e-4 proven invisible)
  auto hiddenHi = [&](const half8* bh, const half8* blo,
                      const _Float16* srcHi, _Float16* dstHi,
                      const float* bias) {
    f32x4 a0 = {0.f, 0.f, 0.f, 0.f};
    f32x4 a2 = {0.f, 0.f, 0.f, 0.f};
#pragma unroll
    for (int kc = 0; kc < 4; ++kc) {
      half8 ah = *(const half8*)(srcHi + row * 136 + kc * 32 + g * 8);
      a0 = __builtin_amdgcn_mfma_f32_16x16x32_f16(ah, bh[kc], a0, 0, 0, 0);
      a2 = __builtin_amdgcn_mfma_f32_16x16x32_f16(ah, blo[kc], a2, 0, 0, 0);
    }
    f32x4 acc = a0 + a2;
    int n = w * 16 + row;
    float bv = bias[n];
#pragma unroll
    for (int r = 0; r < 4; ++r) {
      float v = fmaxf(acc[r] + bv, 0.f);
      dstHi[(g * 4 + r) * 136 + n] = (_Float16)v;
    }
  };

  __syncthreads();

  if (w < 4) out_gemm(0, gb0, w, row, g, zS, ws, biasS, out);

#pragma unroll 1
  for (int t = 0; t < 31; ++t) {
#pragma unroll 1
    for (int s = 0; s < 4; ++s) {
      // ---- dx: 16x16 = 256 entries
      if (tid < 256) {
        int b = tid >> 4, i = tid & 15;
        const float* cr = coeffs + ((size_t)(gb0 + b) * 31 + t) * 64;
        float frac = (s == 3) ? 1.f : s * (1.f / 3.f);
        dxS[b * 16 + i] = cr[16 + i] + (cr[32 + i] + cr[48 + i] * frac) * frac;
      }
      // ---- zz = stage argument (one f32x4 per thread: 16*32 = 512)
      {
        int b = tid >> 5;
        int c = (tid & 31) * 4;
        float* zp = zS + b * 132 + c;
        f32x4 z = *(const f32x4*)zp;
        f32x4 v = z;
        if (s == 1) {
          f32x4 k1 = *(const f32x4*)(kS + b * 128 + c);
          v = z + k1 * (1.f / 3.f);
        } else if (s == 2) {
          f32x4 k1 = *(const f32x4*)(kS + b * 128 + c);
          f32x4 k2 = *(const f32x4*)(kS + (16 + b) * 128 + c);
          v = z + k2 - k1 * (1.f / 3.f);
        } else if (s == 3) {
          f32x4 k1 = *(const f32x4*)(kS + b * 128 + c);
          f32x4 k2 = *(const f32x4*)(kS + (16 + b) * 128 + c);
          f32x4 k3 = *(const f32x4*)(kS + (32 + b) * 128 + c);
          v = z + k1 - k2 + k3;
          *(f32x4*)zp = z + 0.125f * (k1 + 3.f * (k2 + k3));  // + k4/8 in G5
        }
        half4 hi, lo;
#pragma unroll
        for (int j = 0; j < 4; ++j) {
          _Float16 h = (_Float16)v[j];
          hi[j] = h;
          lo[j] = (_Float16)(v[j] - (float)h);
        }
        *(half4*)(bufAHi + b * 136 + c) = hi;
        *(half4*)(bufALo + b * 136 + c) = lo;
      }
      __syncthreads();

      // ---- G1..G4: zero global loads (weights pinned in VGPRs)
      hiddenG1(w0h, w0l, bufBHi, biasS);
      __syncthreads();
      hiddenHi(w1h, w1l, bufBHi, bufAHi, biasS + 128);
      __syncthreads();
      hiddenHi(w2h, w2l, bufAHi, bufBHi, biasS + 256);
      __syncthreads();
      hiddenHi(w3h, w3l, bufBHi, bufAHi, biasS + 384);
      __syncthreads();

      // ---- G5: f = tanh(h @ Wf^T + bf); k = einsum(f, dx).
      // A hi-only (f16), Wf hi-only (the sole remaining load stream).
      float dxr[4], dx2[4];
#pragma unroll
      for (int r = 0; r < 4; ++r) {
        dxr[r] = dxS[(g * 4 + r) * 16 + row];
        dx2[r] = dxr[r] + dxr[r];
      }
      half8 Ah[4];
#pragma unroll
      for (int kc = 0; kc < 4; ++kc)
        Ah[kc] = *(const half8*)(bufAHi + row * 136 + kc * 32 + g * 8);
#pragma unroll 4
      for (int it = 0; it < 16; ++it) {
        int nt = w * 16 + it;  // = h index
        const _Float16* bhp = ws + OFF_WFHI + nt * 2048;
        f32x4 acc = {0.f, 0.f, 0.f, 0.f};
#pragma unroll
        for (int kc = 0; kc < 4; ++kc) {
          half8 bh = *(const half8*)(bhp + (kc * 64 + lane) * 8);
          acc = __builtin_amdgcn_mfma_f32_16x16x32_f16(Ah[kc], bh, acc, 0, 0, 0);
        }
        float bv = biasS[512 + nt * 16 + row];  // row = i (col of tile)
        float ts[4];
#pragma unroll
        for (int r = 0; r < 4; ++r) {
          float x = acc[r] + bv;
          // tanh(x)*dx = dx - 2*dx * rcp(exp(2x)+1); inf-safe at both ends
          float e2 = __expf(x + x);
          float rc = __builtin_amdgcn_rcpf(e2 + 1.f);
          ts[r] = __builtin_fmaf(-dx2[r], rc, dxr[r]);
        }
#pragma unroll
        for (int r = 0; r < 4; ++r) {
          ts[r] = dpp_red<0x111>(ts[r]);   // row_shr:1
          ts[r] = dpp_red<0x112>(ts[r]);   // row_shr:2
          ts[r] = dpp_red<0x114>(ts[r]);   // row_shr:4
          ts[r] = dpp_red<0x118>(ts[r]);   // row_shr:8 -> lane15 = sum
        }
        if (row == 15) {
#pragma unroll
          for (int r = 0; r < 4; ++r) {
            if (s < 3) kS[(s * 16 + g * 4 + r) * 128 + nt] = ts[r];
            else       zS[(g * 4 + r) * 132 + nt] += 0.125f * ts[r];
          }
        }
      }
      __syncthreads();
    }
    if (w < 4) out_gemm(t + 1, gb0, w, row, g, zS, ws, biasS, out);
  }
}

extern "C" void kernel_launch(void* const* d_in, const int* in_sizes, int n_in,
                              void* d_out, int out_size, void* d_ws, size_t ws_size,
                              hipStream_t stream) {
  const float* coeffs = (const float*)d_in[1];
  const float* W_init = (const float*)d_in[2];
  const float* b_init = (const float*)d_in[3];
  const float* W0     = (const float*)d_in[4];
  const float* b0     = (const float*)d_in[5];
  const float* Wl     = (const float*)d_in[6];
  const float* bl     = (const float*)d_in[7];
  const float* Wf     = (const float*)d_in[8];
  const float* bf     = (const float*)d_in[9];
  const float* Wlast  = (const float*)d_in[10];
  const float* b_last = (const float*)d_in[11];
  _Float16* ws = (_Float16*)d_ws;
  float* out = (float*)d_out;

  prep_kernel<<<1312, 256, 0, stream>>>(W0, Wl, Wf, Wlast, ws);
  cde_kernel<<<16, 512, 0, stream>>>(coeffs, W_init, b_init, b0, bl, bf, b_last,
                                     ws, out);
}